// Round 7
// baseline (52.953 us; speedup 1.0000x reference)
//
#include <hip/hip_runtime.h>
#include <hip/hip_cooperative_groups.h>

namespace cg = cooperative_groups;

#define NA 192
#define RCUT_R 5.0f
#define RCUT_A 3.5f
#define NFEAT 96
#define NH 128
#define PI_F 3.14159265358979323846f

__device__ __forceinline__ float app_gauss(float x) {
    float a = 1.0f / (1.0f + x * (1.0f / 64.0f));
    float a2 = a * a, a4 = a2 * a2, a8 = a4 * a4, a16 = a8 * a8, a32 = a16 * a16;
    return a32 * a32;
}

__device__ __forceinline__ float fast_tanh(float x) {
    float ax = fabsf(x);
    float e = __expf(-2.0f * ax);
    float t = (1.0f - e) / (1.0f + e);
    return (x < 0.0f) ? -t : t;
}

__global__ __launch_bounds__(512) void fused_kernel(
    const float* __restrict__ pos, const float* __restrict__ spec,
    const float* __restrict__ Rs, const float* __restrict__ Rs_ang,
    const float* __restrict__ theta_s, const float* __restrict__ width,
    const float* __restrict__ width_ang, const float* __restrict__ zeta,
    const float* __restrict__ W1, const float* __restrict__ b1,
    const float* __restrict__ W2, const float* __restrict__ b2,
    const float* __restrict__ W3, const float* __restrict__ b3,
    float* __restrict__ e_atom,
    float* __restrict__ out)
{
    const int i = blockIdx.x;
    const int tid = threadIdx.x;
    const int lane = tid & 63;
    const int wid = tid >> 6;

    __shared__ float s_r[NA], s_sfc[NA];
    __shared__ float nb_x[NA], nb_y[NA], nb_z[NA], nb_r[NA], nb_w[NA];
    __shared__ float s_feat[NFEAT];
    __shared__ float s_red[16 * 32];
    __shared__ float s_ang[8][64];
    __shared__ float s_part[4][NH];
    __shared__ float s_h[NH];
    __shared__ int s_wcnt[8];
    __shared__ int s_nj;

    // ---- stage pairwise data (threads 0..191) ----
    float dx = 0.f, dy = 0.f, dz = 0.f, rr = 0.f, fw = 0.f;
    bool flag = false;
    if (tid < NA) {
        int j = tid;
        float px = pos[3 * i + 0], py = pos[3 * i + 1], pz = pos[3 * i + 2];
        dx = px - pos[3 * j + 0];
        dy = py - pos[3 * j + 1];
        dz = pz - pos[3 * j + 2];
        rr = sqrtf(dx * dx + dy * dy + dz * dz + 1e-12f);
        s_r[j] = rr;
        float fcr = (j != i && rr <= RCUT_R)
                    ? 0.5f * (1.0f + __cosf(PI_F * rr * (1.0f / RCUT_R))) : 0.0f;
        s_sfc[j] = fcr * spec[j];
        flag = (j != i) && (rr <= RCUT_A);
        float fca = flag ? 0.5f * (1.0f + __cosf(PI_F * rr * (1.0f / RCUT_A))) : 0.0f;
        fw = fca * spec[j];
    }
    unsigned long long mask = __ballot(flag);
    if (lane == 0) s_wcnt[wid] = __popcll(mask);
    __syncthreads();                       // barrier 1
    if (flag) {
        int off = 0;
        for (int w = 0; w < wid; ++w) off += s_wcnt[w];
        int p = off + __popcll(mask & ((1ull << lane) - 1ull));
        nb_x[p] = dx; nb_y[p] = dy; nb_z[p] = dz; nb_r[p] = rr; nb_w[p] = fw;
    }
    if (tid == 0) {
        int t = 0;
        for (int w = 0; w < 8; ++w) t += s_wcnt[w];
        s_nj = t;
    }

    // ---- radial partials ----
    {
        const int s = tid & 31;
        const int g = tid >> 5;            // 16 groups
        const float Rsv = Rs[s];
        const float w0 = width[0];
        float acc = 0.0f;
        for (int j = g; j < NA; j += 16) {
            float d = s_r[j] - Rsv;
            acc += app_gauss(w0 * d * d) * s_sfc[j];
        }
        s_red[g * 32 + s] = acc;
    }
    __syncthreads();                       // barrier 2: nb_*, s_nj, s_red
    if (tid < 32) {
        float a = 0.0f;
        for (int g = 0; g < 16; ++g) a += s_red[g * 32 + tid];
        s_feat[tid] = a;
    }

    // ---- angular: lane owns (s,t); wave takes npr/8 pairs; shuffle-broadcast scalars ----
    {
        const int nj = s_nj;
        const int npr = nj * (nj - 1) / 2;
        const int tA = lane & 7;
        const int sA = lane >> 3;
        const float wang = width_ang[0];
        const float zet = zeta[0];
        const float pref = __expf((1.0f - zet) * 0.6931471805599453f);  // 2^(1-zeta)
        const float th = theta_s[tA];
        const float cth = __cosf(th), sth = __sinf(th);
        const float RsAl = Rs_ang[sA];
        const bool z8 = (zet == 8.0f);
        float acc = 0.0f;
        const int cnt = (npr + 7) >> 3;
        const int p0 = wid * cnt;
        const int p1 = min(npr, p0 + cnt);
        for (int base = p0; base < p1; base += 64) {
            const int m = min(64, p1 - base);
            float my_ct = 0.f, my_st = 0.f, my_w2 = 0.f, my_rbar = 0.f;
            if (lane < m) {
                int p = base + lane;
                int b = (int)((1.0f + __fsqrt_rn(1.0f + 8.0f * (float)p)) * 0.5f);
                if (b * (b - 1) / 2 > p) --b;
                else if ((b + 1) * b / 2 <= p) ++b;
                int a = p - b * (b - 1) / 2;
                float ra = nb_r[a], rb = nb_r[b];
                float dot = nb_x[a] * nb_x[b] + nb_y[a] * nb_y[b] + nb_z[a] * nb_z[b];
                float ct = dot / (ra * rb + 1e-12f);
                ct = fminf(fmaxf(ct, -1.0f + 1e-6f), 1.0f - 1e-6f);
                my_ct = ct;
                my_st = __fsqrt_rn(1.0f - ct * ct);
                my_w2 = nb_w[a] * nb_w[b];
                my_rbar = 0.5f * (ra + rb);
            }
            if (z8) {
                for (int r = 0; r < m; ++r) {
                    float ct = __shfl(my_ct, r), st = __shfl(my_st, r);
                    float w2 = __shfl(my_w2, r), rbar = __shfl(my_rbar, r);
                    float d = rbar - RsAl;
                    float radv = app_gauss(wang * d * d);
                    float bse = fmaxf(1.0f + ct * cth + st * sth, 1e-7f);
                    float q2 = bse * bse, q4 = q2 * q2, q8 = q4 * q4;
                    acc += w2 * radv * q8;
                }
            } else {
                for (int r = 0; r < m; ++r) {
                    float ct = __shfl(my_ct, r), st = __shfl(my_st, r);
                    float w2 = __shfl(my_w2, r), rbar = __shfl(my_rbar, r);
                    float d = rbar - RsAl;
                    float radv = app_gauss(wang * d * d);
                    float bse = fmaxf(1.0f + ct * cth + st * sth, 1e-7f);
                    float pw = __expf(zet * __logf(bse));
                    acc += w2 * radv * pw;
                }
            }
        }
        s_ang[wid][lane] = acc * pref;
    }
    __syncthreads();                       // barrier 3: s_ang + s_feat[0:32]
    if (tid < 64) {
        float a = 0.0f;
#pragma unroll
        for (int w = 0; w < 8; ++w) a += s_ang[w][tid];
        s_feat[32 + tid] = a;
    }
    __syncthreads();                       // barrier 4: full s_feat

    // ---- MLP: 96 -> 128 -> 128 -> 1, all 512 threads ----
    {
        const int o = tid & (NH - 1), q = tid >> 7;
        float acc = 0.0f;
        const int f0 = q * 24;
        for (int f = f0; f < f0 + 24; ++f) acc += s_feat[f] * W1[f * NH + o];
        s_part[q][o] = acc;
    }
    __syncthreads();
    if (tid < NH)
        s_h[tid] = fast_tanh(b1[tid] + s_part[0][tid] + s_part[1][tid]
                                     + s_part[2][tid] + s_part[3][tid]);
    __syncthreads();
    {
        const int o = tid & (NH - 1), q = tid >> 7;
        float acc = 0.0f;
        const int f0 = q * 32;
        for (int f = f0; f < f0 + 32; ++f) acc += s_h[f] * W2[f * NH + o];
        s_part[q][o] = acc;
    }
    __syncthreads();
    if (tid < NH)
        s_h[tid] = fast_tanh(b2[tid] + s_part[0][tid] + s_part[1][tid]
                                     + s_part[2][tid] + s_part[3][tid]);
    __syncthreads();
    if (tid < NH) {
        float v = s_h[tid] * W3[tid];
        v += __shfl_xor(v, 1);  v += __shfl_xor(v, 2);  v += __shfl_xor(v, 4);
        v += __shfl_xor(v, 8);  v += __shfl_xor(v, 16); v += __shfl_xor(v, 32);
        if (lane == 0) s_part[0][wid] = v;   // wid = 0 or 1
    }
    __syncthreads();
    if (tid == 0) e_atom[i] = s_part[0][0] + s_part[0][1] + b3[0];

    // ---- grid-wide barrier (cooperative), then block 0 reduces ----
    cg::this_grid().sync();

    if (blockIdx.x == 0 && tid < 64) {
        float v = 0.0f;
        for (int k = tid; k < NA; k += 64) v += e_atom[k];
        v += __shfl_xor(v, 1);  v += __shfl_xor(v, 2);  v += __shfl_xor(v, 4);
        v += __shfl_xor(v, 8);  v += __shfl_xor(v, 16); v += __shfl_xor(v, 32);
        if (tid == 0) out[0] = v;
    }
}

extern "C" void kernel_launch(void* const* d_in, const int* in_sizes, int n_in,
                              void* d_out, int out_size, void* d_ws, size_t ws_size,
                              hipStream_t stream)
{
    const float* pos       = (const float*)d_in[0];
    const float* spec      = (const float*)d_in[1];
    const float* Rs        = (const float*)d_in[2];
    const float* Rs_ang    = (const float*)d_in[3];
    const float* theta_s   = (const float*)d_in[4];
    const float* width     = (const float*)d_in[5];
    const float* width_ang = (const float*)d_in[6];
    const float* zeta      = (const float*)d_in[7];
    const float* W1        = (const float*)d_in[8];
    const float* b1        = (const float*)d_in[9];
    const float* W2        = (const float*)d_in[10];
    const float* b2        = (const float*)d_in[11];
    const float* W3        = (const float*)d_in[12];
    const float* b3        = (const float*)d_in[13];

    float* e_atom = (float*)d_ws;
    float* out = (float*)d_out;

    void* args[] = {
        (void*)&pos, (void*)&spec, (void*)&Rs, (void*)&Rs_ang, (void*)&theta_s,
        (void*)&width, (void*)&width_ang, (void*)&zeta,
        (void*)&W1, (void*)&b1, (void*)&W2, (void*)&b2, (void*)&W3, (void*)&b3,
        (void*)&e_atom, (void*)&out
    };

    hipLaunchCooperativeKernel((const void*)fused_kernel, dim3(NA), dim3(512),
                               args, 0, stream);
}

// Round 8
// 19.970 us; speedup vs baseline: 2.6517x; 2.6517x over previous
//
#include <hip/hip_runtime.h>

#define NA 192
#define RCUT_R 5.0f
#define RCUT_A 3.5f
#define NFEAT 96
#define NH 128
#define PI_F 3.14159265358979323846f

__device__ __forceinline__ float app_gauss(float x) {
    float a = 1.0f / (1.0f + x * (1.0f / 64.0f));
    float a2 = a * a, a4 = a2 * a2, a8 = a4 * a4, a16 = a8 * a8, a32 = a16 * a16;
    return a32 * a32;
}

__device__ __forceinline__ float fast_tanh(float x) {
    float ax = fabsf(x);
    float e = __expf(-2.0f * ax);
    float t = (1.0f - e) / (1.0f + e);
    return (x < 0.0f) ? -t : t;
}

__global__ __launch_bounds__(512) void fused_kernel(
    const float* __restrict__ pos, const float* __restrict__ spec,
    const float* __restrict__ Rs, const float* __restrict__ Rs_ang,
    const float* __restrict__ theta_s, const float* __restrict__ width,
    const float* __restrict__ width_ang, const float* __restrict__ zeta,
    const float* __restrict__ W1, const float* __restrict__ b1,
    const float* __restrict__ W2, const float* __restrict__ b2,
    const float* __restrict__ W3, const float* __restrict__ b3,
    float* __restrict__ e_atom)
{
    const int i = blockIdx.x;
    const int tid = threadIdx.x;
    const int lane = tid & 63;
    const int wid = tid >> 6;

    __shared__ float s_r[NA], s_sfc[NA];
    __shared__ float nb_x[NA], nb_y[NA], nb_z[NA], nb_r[NA], nb_w[NA];
    __shared__ float s_feat[NFEAT];
    __shared__ float s_red[16 * 32];
    __shared__ float s_ang[8][64];
    __shared__ float s_h[NH];
    __shared__ float s_fin[8];
    __shared__ int s_wcnt[8];
    __shared__ int s_nj;

    // ---- stage pairwise data (threads 0..191) ----
    float dx = 0.f, dy = 0.f, dz = 0.f, rr = 0.f, fw = 0.f;
    bool flag = false;
    if (tid < NA) {
        int j = tid;
        float px = pos[3 * i + 0], py = pos[3 * i + 1], pz = pos[3 * i + 2];
        dx = px - pos[3 * j + 0];
        dy = py - pos[3 * j + 1];
        dz = pz - pos[3 * j + 2];
        rr = sqrtf(dx * dx + dy * dy + dz * dz + 1e-12f);
        s_r[j] = rr;
        float fcr = (j != i && rr <= RCUT_R)
                    ? 0.5f * (1.0f + __cosf(PI_F * rr * (1.0f / RCUT_R))) : 0.0f;
        s_sfc[j] = fcr * spec[j];
        flag = (j != i) && (rr <= RCUT_A);
        float fca = flag ? 0.5f * (1.0f + __cosf(PI_F * rr * (1.0f / RCUT_A))) : 0.0f;
        fw = fca * spec[j];
    }
    unsigned long long mask = __ballot(flag);
    if (lane == 0) s_wcnt[wid] = __popcll(mask);
    __syncthreads();                       // barrier 1
    if (flag) {
        int off = 0;
        for (int w = 0; w < wid; ++w) off += s_wcnt[w];
        int p = off + __popcll(mask & ((1ull << lane) - 1ull));
        nb_x[p] = dx; nb_y[p] = dy; nb_z[p] = dz; nb_r[p] = rr; nb_w[p] = fw;
    }
    if (tid == 0) {
        int t = 0;
        for (int w = 0; w < 8; ++w) t += s_wcnt[w];
        s_nj = t;
    }

    // ---- radial partials ----
    {
        const int s = tid & 31;
        const int g = tid >> 5;            // 16 groups
        const float Rsv = Rs[s];
        const float w0 = width[0];
        float acc = 0.0f;
        for (int j = g; j < NA; j += 16) {
            float d = s_r[j] - Rsv;
            acc += app_gauss(w0 * d * d) * s_sfc[j];
        }
        s_red[g * 32 + s] = acc;
    }
    __syncthreads();                       // barrier 2: nb_*, s_nj, s_red
    if (tid < 32) {
        float a = 0.0f;
        for (int g = 0; g < 16; ++g) a += s_red[g * 32 + tid];
        s_feat[tid] = a;
    }

    // ---- angular: lane owns (s,t); wave takes npr/8 pairs; shuffle-broadcast scalars ----
    {
        const int nj = s_nj;
        const int npr = nj * (nj - 1) / 2;
        const int tA = lane & 7;
        const int sA = lane >> 3;
        const float wang = width_ang[0];
        const float zet = zeta[0];
        const float pref = __expf((1.0f - zet) * 0.6931471805599453f);  // 2^(1-zeta)
        const float th = theta_s[tA];
        const float cth = __cosf(th), sth = __sinf(th);
        const float RsAl = Rs_ang[sA];
        const bool z8 = (zet == 8.0f);
        float acc = 0.0f;
        const int cnt = (npr + 7) >> 3;
        const int p0 = wid * cnt;
        const int p1 = min(npr, p0 + cnt);
        for (int base = p0; base < p1; base += 64) {
            const int m = min(64, p1 - base);
            float my_ct = 0.f, my_st = 0.f, my_w2 = 0.f, my_rbar = 0.f;
            if (lane < m) {
                int p = base + lane;
                int b = (int)((1.0f + __fsqrt_rn(1.0f + 8.0f * (float)p)) * 0.5f);
                if (b * (b - 1) / 2 > p) --b;
                else if ((b + 1) * b / 2 <= p) ++b;
                int a = p - b * (b - 1) / 2;
                float ra = nb_r[a], rb = nb_r[b];
                float dot = nb_x[a] * nb_x[b] + nb_y[a] * nb_y[b] + nb_z[a] * nb_z[b];
                float ct = dot / (ra * rb + 1e-12f);
                ct = fminf(fmaxf(ct, -1.0f + 1e-6f), 1.0f - 1e-6f);
                my_ct = ct;
                my_st = __fsqrt_rn(1.0f - ct * ct);
                my_w2 = nb_w[a] * nb_w[b];
                my_rbar = 0.5f * (ra + rb);
            }
            if (z8) {
                for (int r = 0; r < m; ++r) {
                    float ct = __shfl(my_ct, r), st = __shfl(my_st, r);
                    float w2 = __shfl(my_w2, r), rbar = __shfl(my_rbar, r);
                    float d = rbar - RsAl;
                    float radv = app_gauss(wang * d * d);
                    float bse = fmaxf(1.0f + ct * cth + st * sth, 1e-7f);
                    float q2 = bse * bse, q4 = q2 * q2, q8 = q4 * q4;
                    acc += w2 * radv * q8;
                }
            } else {
                for (int r = 0; r < m; ++r) {
                    float ct = __shfl(my_ct, r), st = __shfl(my_st, r);
                    float w2 = __shfl(my_w2, r), rbar = __shfl(my_rbar, r);
                    float d = rbar - RsAl;
                    float radv = app_gauss(wang * d * d);
                    float bse = fmaxf(1.0f + ct * cth + st * sth, 1e-7f);
                    float pw = __expf(zet * __logf(bse));
                    acc += w2 * radv * pw;
                }
            }
        }
        s_ang[wid][lane] = acc * pref;
    }
    __syncthreads();                       // barrier 3: s_ang + s_feat[0:32]
    if (tid < 64) {
        float a = 0.0f;
#pragma unroll
        for (int w = 0; w < 8; ++w) a += s_ang[w][tid];
        s_feat[32 + tid] = a;
    }
    __syncthreads();                       // barrier 4: full s_feat

    // ---- MLP layer 1: 96 -> 128; output o owned by a 4-lane quad in one wave ----
    {
        const int o = wid * 16 + (lane >> 2);   // [0,128)
        const int q = lane & 3;
        float acc = 0.0f;
        const int f0 = q * 24;
#pragma unroll
        for (int f = f0; f < f0 + 24; ++f) acc += s_feat[f] * W1[f * NH + o];
        acc += __shfl_xor(acc, 1);
        acc += __shfl_xor(acc, 2);
        if (q == 0) s_h[o] = fast_tanh(b1[o] + acc);
    }
    __syncthreads();                       // barrier 5: s_h (layer-1 out)

    // ---- MLP layer 2: 128 -> 128 ----
    {
        const int o = wid * 16 + (lane >> 2);
        const int q = lane & 3;
        float acc = 0.0f;
        const int f0 = q * 32;
#pragma unroll
        for (int f = f0; f < f0 + 32; ++f) acc += s_h[f] * W2[f * NH + o];
        acc += __shfl_xor(acc, 1);
        acc += __shfl_xor(acc, 2);
        if (q == 0) s_fin[wid] = 0.0f;     // dummy to keep s_fin defined; overwritten below
        if (q == 0) s_red[o] = fast_tanh(b2[o] + acc);   // reuse s_red[0:128] as h2
    }
    __syncthreads();                       // barrier 6: h2 ready

    // ---- layer 3 + per-block sum ----
    if (tid < NH) {
        float v = s_red[tid] * W3[tid];
        v += __shfl_xor(v, 1);  v += __shfl_xor(v, 2);  v += __shfl_xor(v, 4);
        v += __shfl_xor(v, 8);  v += __shfl_xor(v, 16); v += __shfl_xor(v, 32);
        if (lane == 0) s_fin[wid] = v;     // wid = 0 or 1
    }
    __syncthreads();                       // barrier 7
    if (tid == 0) e_atom[i] = s_fin[0] + s_fin[1] + b3[0];
}

__global__ __launch_bounds__(64) void reduce_kernel(const float* __restrict__ e_atom,
                                                    float* __restrict__ out)
{
    int tid = threadIdx.x;
    float v = 0.0f;
    if (tid < 48) {
        float4 e4 = ((const float4*)e_atom)[tid];
        v = ((e4.x + e4.y) + (e4.z + e4.w));
    }
    v += __shfl_xor(v, 1);  v += __shfl_xor(v, 2);  v += __shfl_xor(v, 4);
    v += __shfl_xor(v, 8);  v += __shfl_xor(v, 16); v += __shfl_xor(v, 32);
    if (tid == 0) out[0] = v;
}

extern "C" void kernel_launch(void* const* d_in, const int* in_sizes, int n_in,
                              void* d_out, int out_size, void* d_ws, size_t ws_size,
                              hipStream_t stream)
{
    const float* pos       = (const float*)d_in[0];
    const float* spec      = (const float*)d_in[1];
    const float* Rs        = (const float*)d_in[2];
    const float* Rs_ang    = (const float*)d_in[3];
    const float* theta_s   = (const float*)d_in[4];
    const float* width     = (const float*)d_in[5];
    const float* width_ang = (const float*)d_in[6];
    const float* zeta      = (const float*)d_in[7];
    const float* W1        = (const float*)d_in[8];
    const float* b1        = (const float*)d_in[9];
    const float* W2        = (const float*)d_in[10];
    const float* b2        = (const float*)d_in[11];
    const float* W3        = (const float*)d_in[12];
    const float* b3        = (const float*)d_in[13];

    float* e_atom = (float*)d_ws;

    fused_kernel<<<NA, 512, 0, stream>>>(pos, spec, Rs, Rs_ang, theta_s, width,
                                         width_ang, zeta, W1, b1, W2, b2, W3, b3,
                                         e_atom);
    reduce_kernel<<<1, 64, 0, stream>>>(e_atom, (float*)d_out);
}

// Round 9
// 16.299 us; speedup vs baseline: 3.2489x; 1.2252x over previous
//
#include <hip/hip_runtime.h>

#define NA 192
#define RCUT_R 5.0f
#define RCUT_A 3.5f
#define NFEAT 96
#define NH 128
#define PI_F 3.14159265358979323846f

__device__ __forceinline__ float app_gauss(float x) {
    float a = 1.0f / (1.0f + x * (1.0f / 64.0f));
    float a2 = a * a, a4 = a2 * a2, a8 = a4 * a4, a16 = a8 * a8, a32 = a16 * a16;
    return a32 * a32;
}

__device__ __forceinline__ float fast_tanh(float x) {
    float ax = fabsf(x);
    float e = __expf(-2.0f * ax);
    float t = (1.0f - e) / (1.0f + e);
    return (x < 0.0f) ? -t : t;
}

__global__ __launch_bounds__(512) void fused_kernel(
    const float* __restrict__ pos, const float* __restrict__ spec,
    const float* __restrict__ Rs, const float* __restrict__ Rs_ang,
    const float* __restrict__ theta_s, const float* __restrict__ width,
    const float* __restrict__ width_ang, const float* __restrict__ zeta,
    const float* __restrict__ W1, const float* __restrict__ b1,
    const float* __restrict__ W2, const float* __restrict__ b2,
    const float* __restrict__ W3, const float* __restrict__ b3,
    float* __restrict__ e_atom)
{
    const int i = blockIdx.x;
    const int tid = threadIdx.x;
    const int lane = tid & 63;
    const int wid = tid >> 6;
    const int o = tid & (NH - 1);          // MLP output slot [0,128)
    const int q = tid >> 7;                // quarter [0,4)

    __shared__ float s_r[NA], s_sfc[NA];
    __shared__ float nb_x[NA], nb_y[NA], nb_z[NA], nb_r[NA], nb_w[NA];
    __shared__ float s_feat[NFEAT];
    __shared__ float s_red[16 * 32];
    __shared__ float s_ang[8][64];
    __shared__ float s_part[4][NH];
    __shared__ float s_h[NH];
    __shared__ float s_fin[8];
    __shared__ int s_wcnt[8];
    __shared__ int s_nj;

    // ---- weight prefetch into registers (issue early, consume in MLP) ----
    // Coalesced: 128 consecutive threads (o) read consecutive addresses per f.
    float w1r[24], w2r[32];
#pragma unroll
    for (int k = 0; k < 24; ++k) w1r[k] = W1[(q * 24 + k) * NH + o];
#pragma unroll
    for (int k = 0; k < 32; ++k) w2r[k] = W2[(q * 32 + k) * NH + o];
    const float w3r = (tid < NH) ? W3[tid] : 0.0f;
    const float b1r = b1[o];
    const float b2r = b2[o];

    // ---- stage pairwise data (threads 0..191) ----
    float dx = 0.f, dy = 0.f, dz = 0.f, rr = 0.f, fw = 0.f;
    bool flag = false;
    if (tid < NA) {
        int j = tid;
        float px = pos[3 * i + 0], py = pos[3 * i + 1], pz = pos[3 * i + 2];
        dx = px - pos[3 * j + 0];
        dy = py - pos[3 * j + 1];
        dz = pz - pos[3 * j + 2];
        rr = sqrtf(dx * dx + dy * dy + dz * dz + 1e-12f);
        s_r[j] = rr;
        float fcr = (j != i && rr <= RCUT_R)
                    ? 0.5f * (1.0f + __cosf(PI_F * rr * (1.0f / RCUT_R))) : 0.0f;
        s_sfc[j] = fcr * spec[j];
        flag = (j != i) && (rr <= RCUT_A);
        float fca = flag ? 0.5f * (1.0f + __cosf(PI_F * rr * (1.0f / RCUT_A))) : 0.0f;
        fw = fca * spec[j];
    }
    unsigned long long mask = __ballot(flag);
    if (lane == 0) s_wcnt[wid] = __popcll(mask);
    __syncthreads();                       // barrier 1
    if (flag) {
        int off = 0;
        for (int w = 0; w < wid; ++w) off += s_wcnt[w];
        int p = off + __popcll(mask & ((1ull << lane) - 1ull));
        nb_x[p] = dx; nb_y[p] = dy; nb_z[p] = dz; nb_r[p] = rr; nb_w[p] = fw;
    }
    if (tid == 0) {
        int t = 0;
        for (int w = 0; w < 8; ++w) t += s_wcnt[w];
        s_nj = t;
    }

    // ---- radial partials ----
    {
        const int s = tid & 31;
        const int g = tid >> 5;            // 16 groups
        const float Rsv = Rs[s];
        const float w0 = width[0];
        float acc = 0.0f;
        for (int j = g; j < NA; j += 16) {
            float d = s_r[j] - Rsv;
            acc += app_gauss(w0 * d * d) * s_sfc[j];
        }
        s_red[g * 32 + s] = acc;
    }
    __syncthreads();                       // barrier 2: nb_*, s_nj, s_red
    if (tid < 32) {
        float a = 0.0f;
        for (int g = 0; g < 16; ++g) a += s_red[g * 32 + tid];
        s_feat[tid] = a;
    }

    // ---- angular: lane owns (s,t); wave takes npr/8 pairs; shuffle-broadcast scalars ----
    {
        const int nj = s_nj;
        const int npr = nj * (nj - 1) / 2;
        const int tA = lane & 7;
        const int sA = lane >> 3;
        const float wang = width_ang[0];
        const float zet = zeta[0];
        const float pref = __expf((1.0f - zet) * 0.6931471805599453f);  // 2^(1-zeta)
        const float th = theta_s[tA];
        const float cth = __cosf(th), sth = __sinf(th);
        const float RsAl = Rs_ang[sA];
        const bool z8 = (zet == 8.0f);
        float acc = 0.0f;
        const int cnt = (npr + 7) >> 3;
        const int p0 = wid * cnt;
        const int p1 = min(npr, p0 + cnt);
        for (int base = p0; base < p1; base += 64) {
            const int m = min(64, p1 - base);
            float my_ct = 0.f, my_st = 0.f, my_w2 = 0.f, my_rbar = 0.f;
            if (lane < m) {
                int p = base + lane;
                int b = (int)((1.0f + __fsqrt_rn(1.0f + 8.0f * (float)p)) * 0.5f);
                if (b * (b - 1) / 2 > p) --b;
                else if ((b + 1) * b / 2 <= p) ++b;
                int a = p - b * (b - 1) / 2;
                float ra = nb_r[a], rb = nb_r[b];
                float dot = nb_x[a] * nb_x[b] + nb_y[a] * nb_y[b] + nb_z[a] * nb_z[b];
                float ct = dot / (ra * rb + 1e-12f);
                ct = fminf(fmaxf(ct, -1.0f + 1e-6f), 1.0f - 1e-6f);
                my_ct = ct;
                my_st = __fsqrt_rn(1.0f - ct * ct);
                my_w2 = nb_w[a] * nb_w[b];
                my_rbar = 0.5f * (ra + rb);
            }
            if (z8) {
                for (int r = 0; r < m; ++r) {
                    float ct = __shfl(my_ct, r), st = __shfl(my_st, r);
                    float w2 = __shfl(my_w2, r), rbar = __shfl(my_rbar, r);
                    float d = rbar - RsAl;
                    float radv = app_gauss(wang * d * d);
                    float bse = fmaxf(1.0f + ct * cth + st * sth, 1e-7f);
                    float q2 = bse * bse, q4 = q2 * q2, q8 = q4 * q4;
                    acc += w2 * radv * q8;
                }
            } else {
                for (int r = 0; r < m; ++r) {
                    float ct = __shfl(my_ct, r), st = __shfl(my_st, r);
                    float w2 = __shfl(my_w2, r), rbar = __shfl(my_rbar, r);
                    float d = rbar - RsAl;
                    float radv = app_gauss(wang * d * d);
                    float bse = fmaxf(1.0f + ct * cth + st * sth, 1e-7f);
                    float pw = __expf(zet * __logf(bse));
                    acc += w2 * radv * pw;
                }
            }
        }
        s_ang[wid][lane] = acc * pref;
    }
    __syncthreads();                       // barrier 3: s_ang + s_feat[0:32]
    if (tid < 64) {
        float a = 0.0f;
#pragma unroll
        for (int w = 0; w < 8; ++w) a += s_ang[w][tid];
        s_feat[32 + tid] = a;
    }
    __syncthreads();                       // barrier 4: full s_feat

    // ---- MLP layer 1: 96 -> 128 (weights pre-fetched in regs) ----
    {
        float acc = 0.0f;
#pragma unroll
        for (int k = 0; k < 24; ++k) acc += s_feat[q * 24 + k] * w1r[k];
        s_part[q][o] = acc;
    }
    __syncthreads();                       // barrier 5
    if (tid < NH)
        s_h[tid] = fast_tanh(b1r + s_part[0][tid] + s_part[1][tid]
                                 + s_part[2][tid] + s_part[3][tid]);
    __syncthreads();                       // barrier 6
    // ---- MLP layer 2: 128 -> 128 ----
    {
        float acc = 0.0f;
#pragma unroll
        for (int k = 0; k < 32; ++k) acc += s_h[q * 32 + k] * w2r[k];
        s_part[q][o] = acc;
    }
    __syncthreads();                       // barrier 7
    // ---- layer 3 in-register + per-block sum ----
    if (tid < NH) {
        float h2 = fast_tanh(b2r + s_part[0][tid] + s_part[1][tid]
                                 + s_part[2][tid] + s_part[3][tid]);
        float v = h2 * w3r;
        v += __shfl_xor(v, 1);  v += __shfl_xor(v, 2);  v += __shfl_xor(v, 4);
        v += __shfl_xor(v, 8);  v += __shfl_xor(v, 16); v += __shfl_xor(v, 32);
        if (lane == 0) s_fin[wid] = v;     // wid = 0 or 1
    }
    __syncthreads();                       // barrier 8
    if (tid == 0) e_atom[i] = s_fin[0] + s_fin[1] + b3[0];
}

__global__ __launch_bounds__(64) void reduce_kernel(const float* __restrict__ e_atom,
                                                    float* __restrict__ out)
{
    int tid = threadIdx.x;
    float v = 0.0f;
    if (tid < 48) {
        float4 e4 = ((const float4*)e_atom)[tid];
        v = ((e4.x + e4.y) + (e4.z + e4.w));
    }
    v += __shfl_xor(v, 1);  v += __shfl_xor(v, 2);  v += __shfl_xor(v, 4);
    v += __shfl_xor(v, 8);  v += __shfl_xor(v, 16); v += __shfl_xor(v, 32);
    if (tid == 0) out[0] = v;
}

extern "C" void kernel_launch(void* const* d_in, const int* in_sizes, int n_in,
                              void* d_out, int out_size, void* d_ws, size_t ws_size,
                              hipStream_t stream)
{
    const float* pos       = (const float*)d_in[0];
    const float* spec      = (const float*)d_in[1];
    const float* Rs        = (const float*)d_in[2];
    const float* Rs_ang    = (const float*)d_in[3];
    const float* theta_s   = (const float*)d_in[4];
    const float* width     = (const float*)d_in[5];
    const float* width_ang = (const float*)d_in[6];
    const float* zeta      = (const float*)d_in[7];
    const float* W1        = (const float*)d_in[8];
    const float* b1        = (const float*)d_in[9];
    const float* W2        = (const float*)d_in[10];
    const float* b2        = (const float*)d_in[11];
    const float* W3        = (const float*)d_in[12];
    const float* b3        = (const float*)d_in[13];

    float* e_atom = (float*)d_ws;

    fused_kernel<<<NA, 512, 0, stream>>>(pos, spec, Rs, Rs_ang, theta_s, width,
                                         width_ang, zeta, W1, b1, W2, b2, W3, b3,
                                         e_atom);
    reduce_kernel<<<1, 64, 0, stream>>>(e_atom, (float*)d_out);
}